// Round 6
// baseline (320.934 us; speedup 1.0000x reference)
//
#include <hip/hip_runtime.h>
#include <math.h>

// Problem dims (fixed by setup_inputs)
#define DD    512
#define CNUM  64
#define SHOTS 16
#define NSUP  1024
#define QNQ   2048
#define REGP  0.1f
#define XKS   4      // xmu split-K parts

// ---------------- workspace layout (in floats) ----------------
static constexpr size_t OFF_L     = 0;                       // 512*512
static constexpr size_t OFF_W     = OFF_L     + 512*512;     // 512*512
static constexpr size_t OFF_MU    = OFF_W     + 512*512;     // 64*512
static constexpr size_t OFF_Y     = OFF_MU    + 64*512;      // 3136*512
static constexpr size_t OFF_Z     = OFF_Y     + 3136*512;    // 3136
static constexpr size_t OFF_WM    = OFF_Z     + 3136;        // 512
static constexpr size_t OFF_U     = OFF_WM    + 512;         // 512
static constexpr size_t OFF_CONST = OFF_U     + 512;         // 32
static constexpr size_t OFF_IDX   = OFF_CONST + 32;          // 1024 ints
static constexpr size_t OFF_RMAP  = OFF_IDX   + 1024;        // 1088 ints
static constexpr size_t OFF_VMU   = OFF_RMAP  + 1088;        // 1088
static constexpr size_t OFF_MUBMU = OFF_VMU   + 1088;        // 64
static constexpr size_t OFF_MUN   = OFF_MUBMU + 64;          // 64
static constexpr size_t OFF_MINV  = OFF_MUN   + 64;          // 64*289
static constexpr size_t OFF_BIAS  = OFF_MINV  + 64*289;      // 64
static constexpr size_t OFF_QB    = OFF_BIAS  + 64;          // 2048
static constexpr size_t OFF_QNRM  = OFF_QB    + 2048;        // 2048
static constexpr size_t OFF_XMU   = OFF_QNRM  + 2048;        // XKS*2048*64
static constexpr size_t OFF_RG    = OFF_XMU   + (size_t)XKS*2048*64; // 1088*2048
static constexpr size_t OFF_RG2   = OFF_RG    + 1088*2048;   // 1088*2048

// consts: 0 kap, 1 scale, 2 common, 3 coef, 4 bias0, 5 jlast,
// 6 cmu_m, 7 cmu_x, 8 D*log(scale), 9 Jinv_last, 10 c_sm, 11 logdetB

// ============ F1: init L/W + consts + classidx (one launch) ============
__global__ __launch_bounds__(256) void f_init(const float* tdiag, const float* tlow,
    const float* kappa, const float* nu, const int* labels,
    float* L, float* W, float* cst, int* idx, int* rowmap) {
  int b = blockIdx.x, tid = threadIdx.x;
  if (b < 1024) {
    int t = b * 256 + tid;
    int i = t / DD, j = t % DD;
    L[t] = (i == j) ? fabsf(tdiag[i]) : (i > j ? tlow[t] : 0.0f);
    W[t] = 0.0f;
  } else if (b == 1024) {
    if (tid == 0) {
      float kap = fabsf(kappa[0]) + 1e-6f;
      float nu_ = fmaxf(nu[0], (float)(DD - 1) + 1e-6f);
      float common = nu_ + (float)SHOTS + 1.0f - (float)DD;
      float scale = (kap + SHOTS + 1.0f) / ((nu_ + SHOTS - DD + 1.0f) * (kap + SHOTS));
      cst[0] = kap;
      cst[1] = scale;
      cst[2] = common;
      cst[3] = 0.5f * (common + DD);
      cst[4] = lgammaf(0.5f * (common + DD)) - lgammaf(0.5f * common)
               - 0.5f * (float)DD * logf(common);
      cst[5] = -(kap + SHOTS);
      cst[6] = kap / (kap + SHOTS);
      cst[7] = 1.0f / (kap + SHOTS);
      cst[8] = (float)DD * logf(scale);
      cst[9] = -1.0f / (kap + SHOTS);
    }
  } else {
    int c = b - 1025;
    if (tid < 64) {
      int lane = tid, cnt = 0;
      for (int i0 = 0; i0 < NSUP; i0 += 64) {
        int lab = labels[i0 + lane];
        unsigned long long m = __ballot(lab == c);
        if (lab == c) {
          int pos = cnt + __popcll(m & ((1ull << lane) - 1ull));
          if (pos < SHOTS) idx[c * SHOTS + pos] = i0 + lane;
        }
        cnt += __popcll(m);
      }
    }
    __syncthreads();
    if (tid < 17)
      rowmap[c * 17 + tid] = (tid < SHOTS) ? (QNQ + idx[c * SHOTS + tid])
                                           : (QNQ + NSUP + c);
  }
}

// ============ F2: mu (+||mu||^2) + trinv diag blocks (one launch) ============
__global__ __launch_bounds__(256) void f_mu_diag(const float* Xs, const float* m,
    const int* idx, const float* cst, float* mu, float* mun,
    const float* L, float* W) {
  __shared__ float red[256];
  __shared__ float Ld[64][65];
  __shared__ float Wd[64][65];
  int b = blockIdx.x, tid = threadIdx.x;
  if (b < 64) {
    int c = b;
    float cm = cst[6], cx = cst[7];
    float acc = 0.0f;
    for (int d = tid; d < DD; d += 256) {
      float s = 0.0f;
      for (int sh = 0; sh < SHOTS; sh++)
        s += Xs[(size_t)idx[c * SHOTS + sh] * DD + d];
      float v = cm * m[d] + cx * s;
      mu[(size_t)c * DD + d] = v;
      acc += v * v;
    }
    red[tid] = acc;
    __syncthreads();
    for (int off = 128; off > 0; off >>= 1) {
      if (tid < off) red[tid] += red[tid + off];
      __syncthreads();
    }
    if (tid == 0) mun[c] = red[0];
  } else {
    int jb = b - 64;
    const float* Lblk = L + (size_t)(jb * 64) * DD + jb * 64;
    if (tid < 64)
      for (int r = 0; r < 64; r++) Ld[r][tid] = Lblk[(size_t)r * DD + tid];
    __syncthreads();
    if (tid < 64) {
      // thread t owns column t; only reads its own column's earlier rows
      for (int i = 0; i < 64; i++) {
        float w = (i == tid) ? 1.0f : 0.0f;
        for (int k = 0; k < i; k++) w -= Ld[i][k] * Wd[k][tid];
        Wd[i][tid] = w / Ld[i][i];
      }
      float* Wblk = W + (size_t)(jb * 64) * DD + jb * 64;
      for (int r = 0; r < 64; r++) Wblk[(size_t)r * DD + tid] = Wd[r][tid];
    }
  }
}

// ---------------- trinv: recursive doubling GEMM tile (64x64 out) ----------------
__device__ __forceinline__ void nn64_body(const float* __restrict__ A, int lda,
                                          const float* __restrict__ B, int ldb,
                                          float* __restrict__ Cd, int ldc,
                                          int k0, int k1, float sgn) {
  __shared__ float As[64][68];
  __shared__ float Bs[64][68];
  int tid = threadIdx.x, tr = tid >> 4, tc = tid & 15;
  float acc[4][4] = {};
  for (int kc = k0; kc < k1; kc += 64) {
    #pragma unroll
    for (int p = 0; p < 4; p++) {
      int f4 = tid + 256 * p;
      int row = f4 >> 4, c4 = f4 & 15;
      *(float4*)&As[row][c4 * 4] = *(const float4*)(A + (size_t)row * lda + kc + c4 * 4);
      *(float4*)&Bs[row][c4 * 4] = *(const float4*)(B + (size_t)(kc + row) * ldb + c4 * 4);
    }
    __syncthreads();
    #pragma unroll
    for (int kk = 0; kk < 64; kk++) {
      float a[4];
      #pragma unroll
      for (int x = 0; x < 4; x++) a[x] = As[tr * 4 + x][kk];
      float4 bv = *(const float4*)&Bs[kk][tc * 4];
      float b[4] = {bv.x, bv.y, bv.z, bv.w};
      #pragma unroll
      for (int x = 0; x < 4; x++)
        #pragma unroll
        for (int y = 0; y < 4; y++) acc[x][y] += a[x] * b[y];
    }
    __syncthreads();
  }
  #pragma unroll
  for (int x = 0; x < 4; x++) {
    float4 v = make_float4(sgn * acc[x][0], sgn * acc[x][1],
                           sgn * acc[x][2], sgn * acc[x][3]);
    *(float4*)(Cd + (size_t)(tr * 4 + x) * ldc + tc * 4) = v;
  }
}

__global__ __launch_bounds__(256) void k_triT(const float* __restrict__ L,
                                              const float* __restrict__ W,
                                              float* __restrict__ T, int s) {
  int h = s >> 1, tiles = h >> 6, per = tiles * tiles;
  int g = blockIdx.x / per, rem = blockIdx.x % per;
  int ti = rem / tiles, tj = rem % tiles;
  int base = g * s;
  const float* A = L + (size_t)(base + h + ti * 64) * DD + base;
  const float* B = W + (size_t)base * DD + base + tj * 64;
  float* Cd = T + (size_t)g * h * h + (size_t)(ti * 64) * h + tj * 64;
  nn64_body(A, DD, B, DD, Cd, h, tj * 64, h, 1.0f);
}

__global__ __launch_bounds__(256) void k_triX(float* __restrict__ W,
                                              const float* __restrict__ T, int s) {
  int h = s >> 1, tiles = h >> 6, per = tiles * tiles;
  int g = blockIdx.x / per, rem = blockIdx.x % per;
  int ti = rem / tiles, tj = rem % tiles;
  int base = g * s;
  const float* A = W + (size_t)(base + h + ti * 64) * DD + base + h;
  const float* B = T + (size_t)g * h * h + tj * 64;
  float* Cd = W + (size_t)(base + h + ti * 64) * DD + base + tj * 64;
  nn64_body(A, DD, B, h, Cd, DD, 0, (ti + 1) * 64, -1.0f);
}

// ---------------- 128x64 NT GEMM tile body (8x4/thread) ----------------
#define GBM 128
#define GBN 64
#define GBK 16
__device__ __forceinline__ void gemm_tile_body(
    const float* __restrict__ A, int aOff, int aM,
    const float* __restrict__ B, int K, int bn, int kend,
    float* __restrict__ Cc, int cRow0, int N) {
  __shared__ float As[GBK][GBM + 4];
  __shared__ float Bs[GBK][GBN + 4];
  int tid = threadIdx.x, tr = tid >> 4, tc = tid & 15;
  float acc[8][4] = {};
  for (int k0 = 0; k0 < kend; k0 += GBK) {
    #pragma unroll
    for (int p = 0; p < 2; p++) {
      int u = tid + 256 * p;
      int row = u >> 2, k4 = u & 3;
      int gr = aOff + row;
      float4 v = make_float4(0.f, 0.f, 0.f, 0.f);
      if (gr < aM) v = *(const float4*)(A + (size_t)gr * K + k0 + k4 * 4);
      As[k4 * 4 + 0][row] = v.x; As[k4 * 4 + 1][row] = v.y;
      As[k4 * 4 + 2][row] = v.z; As[k4 * 4 + 3][row] = v.w;
    }
    {
      int row = tid >> 2, k4 = tid & 3;
      float4 v = *(const float4*)(B + (size_t)(bn + row) * K + k0 + k4 * 4);
      Bs[k4 * 4 + 0][row] = v.x; Bs[k4 * 4 + 1][row] = v.y;
      Bs[k4 * 4 + 2][row] = v.z; Bs[k4 * 4 + 3][row] = v.w;
    }
    __syncthreads();
    #pragma unroll
    for (int kk = 0; kk < GBK; kk++) {
      float4 a0 = *(const float4*)&As[kk][tr * 8];
      float4 a1 = *(const float4*)&As[kk][tr * 8 + 4];
      float4 b0 = *(const float4*)&Bs[kk][tc * 4];
      float a[8] = {a0.x, a0.y, a0.z, a0.w, a1.x, a1.y, a1.z, a1.w};
      float b[4] = {b0.x, b0.y, b0.z, b0.w};
      #pragma unroll
      for (int x = 0; x < 8; x++)
        #pragma unroll
        for (int y = 0; y < 4; y++) acc[x][y] += a[x] * b[y];
    }
    __syncthreads();
  }
  #pragma unroll
  for (int x = 0; x < 8; x++) {
    int lr = tr * 8 + x;
    if (aOff + lr < aM) {
      float4 v = make_float4(acc[x][0], acc[x][1], acc[x][2], acc[x][3]);
      *(float4*)(Cc + (size_t)(cRow0 + lr) * N + bn + tc * 4) = v;
    }
  }
}

// ============ F3: Y-GEMM (128x64, tri-skip) + wm + xmu (one launch) ============
__global__ __launch_bounds__(256) void f_y_wm_xmu(const float* __restrict__ Xq,
    const float* __restrict__ Xs, const float* __restrict__ Mu,
    const float* __restrict__ W, const float* __restrict__ m,
    float* __restrict__ Y, float* __restrict__ wm, float* __restrict__ xmup) {
  __shared__ float Bs2[GBK][GBN + 4];
  __shared__ float As2[GBK][32 + 4];
  int b = blockIdx.x, tid = threadIdx.x;
  if (b < 200) {            // Y = [Xq; Xs; mu] @ W^T; 25 m-tiles x 8 n-tiles
    int mt = b / 8, nt = b % 8;
    int bm = mt * 128, bn = nt * 64;
    const float* A; int aOff, aM;
    if (bm < QNQ)             { A = Xq; aOff = bm;              aM = QNQ;  }
    else if (bm < QNQ + NSUP) { A = Xs; aOff = bm - QNQ;        aM = NSUP; }
    else                      { A = Mu; aOff = bm - QNQ - NSUP; aM = CNUM; }
    gemm_tile_body(A, aOff, aM, W, DD, bn, bn + GBN, Y, bm, DD);
  } else if (b < 328) {     // wm[row] = W[row,:] . m  (4 rows/block)
    int wave = tid / 64, lane = tid % 64;
    int row = (b - 200) * 4 + wave;
    float s = 0.0f;
    for (int j = lane; j < DD; j += 64) s += W[(size_t)row * DD + j] * m[j];
    for (int off = 32; off > 0; off >>= 1) s += __shfl_down(s, off);
    if (lane == 0) wm[row] = s;
  } else {                  // xmu partials: 32 q-rows, split-K=4
    int xb = b - 328;
    int bm = (xb & 63) * 32, kq = xb >> 6;
    int tr = tid >> 4, tc = tid & 15;
    float acc[2][4] = {};
    int k0s = kq * (DD / XKS), k0e = k0s + DD / XKS;
    for (int k0 = k0s; k0 < k0e; k0 += GBK) {
      if (tid < 128) {
        int row = tid >> 2, k4 = tid & 3;
        float4 v = *(const float4*)(Xq + (size_t)(bm + row) * DD + k0 + k4 * 4);
        As2[k4 * 4 + 0][row] = v.x; As2[k4 * 4 + 1][row] = v.y;
        As2[k4 * 4 + 2][row] = v.z; As2[k4 * 4 + 3][row] = v.w;
      }
      {
        int row = tid >> 2, k4 = tid & 3;
        float4 v = *(const float4*)(Mu + (size_t)row * DD + k0 + k4 * 4);
        Bs2[k4 * 4 + 0][row] = v.x; Bs2[k4 * 4 + 1][row] = v.y;
        Bs2[k4 * 4 + 2][row] = v.z; Bs2[k4 * 4 + 3][row] = v.w;
      }
      __syncthreads();
      #pragma unroll
      for (int kk = 0; kk < GBK; kk++) {
        float a[2] = {As2[kk][tr * 2], As2[kk][tr * 2 + 1]};
        float4 b0 = *(const float4*)&Bs2[kk][tc * 4];
        float bb[4] = {b0.x, b0.y, b0.z, b0.w};
        #pragma unroll
        for (int x = 0; x < 2; x++)
          #pragma unroll
          for (int y = 0; y < 4; y++) acc[x][y] += a[x] * bb[y];
      }
      __syncthreads();
    }
    #pragma unroll
    for (int x = 0; x < 2; x++) {
      int q = bm + tr * 2 + x;
      float4 v = make_float4(acc[x][0], acc[x][1], acc[x][2], acc[x][3]);
      *(float4*)(xmup + ((size_t)kq * QNQ + q) * CNUM + tc * 4) = v;
    }
  }
}

// fused: blocks 0..511 compute u[j]; block 512 computes SM consts
__global__ __launch_bounds__(256) void k_uB(const float* W, const float* L,
                                            const float* wm, float* u, float* cst) {
  __shared__ float red[256];
  __shared__ float red2[256];
  int b = blockIdx.x, tid = threadIdx.x;
  if (b < DD) {
    float s = 0.0f;
    for (int i = tid; i < DD; i += 256) s += W[(size_t)i * DD + b] * wm[i];
    red[tid] = s;
    __syncthreads();
    for (int off = 128; off > 0; off >>= 1) {
      if (tid < off) red[tid] += red[tid + off];
      __syncthreads();
    }
    if (tid == 0) u[b] = red[0];
  } else {
    float a = 0.0f, l = 0.0f;
    for (int t = tid; t < DD; t += 256) {
      float w = wm[t]; a += w * w;
      l += logf(fabsf(L[(size_t)t * DD + t]));
    }
    red[tid] = a; red2[tid] = l;
    __syncthreads();
    for (int off = 128; off > 0; off >>= 1) {
      if (tid < off) { red[tid] += red[tid + off]; red2[tid] += red2[tid + off]; }
      __syncthreads();
    }
    if (tid == 0) {
      float kap = cst[0], ss = red[0];
      cst[10] = kap / (1.0f + kap * ss);
      cst[11] = 2.0f * red2[0] + logf(1.0f + kap * ss);
    }
  }
}

// ============ F5: Rg GEMM (128x128, 8x8/thread, split-K=2) + z/qn/qB ============
__global__ __launch_bounds__(256) void f_z_rg(const float* __restrict__ Y,
    const int* __restrict__ rowmap, const float* __restrict__ Xq,
    const float* __restrict__ Xs, const float* __restrict__ mu,
    const float* __restrict__ u, const float* __restrict__ cst,
    float* __restrict__ Rg, float* __restrict__ Rg2,
    float* __restrict__ z, float* __restrict__ qn, float* __restrict__ qB) {
  __shared__ float As[GBK][132];
  __shared__ float Bs[GBK][132];
  int b = blockIdx.x, tid = threadIdx.x;
  if (b < 288) {
    int half = b / 144, rem = b % 144;
    int bm = (rem / 16) * 128, bn = (rem % 16) * 128;
    float* out = half ? Rg2 : Rg;
    int k0s = half * 256;
    int tr = tid >> 4, tc = tid & 15;
    int srow[2];
    #pragma unroll
    for (int p = 0; p < 2; p++) {
      int gr = bm + ((tid + 256 * p) >> 2);
      srow[p] = (gr < 17 * CNUM) ? rowmap[gr] : -1;
    }
    float acc[2][2][4][4] = {};
    for (int k0 = k0s; k0 < k0s + 256; k0 += GBK) {
      #pragma unroll
      for (int p = 0; p < 2; p++) {
        int uu = tid + 256 * p;
        int row = uu >> 2, k4 = uu & 3;
        float4 v = make_float4(0.f, 0.f, 0.f, 0.f);
        if (srow[p] >= 0) v = *(const float4*)(Y + (size_t)srow[p] * DD + k0 + k4 * 4);
        As[k4 * 4 + 0][row] = v.x; As[k4 * 4 + 1][row] = v.y;
        As[k4 * 4 + 2][row] = v.z; As[k4 * 4 + 3][row] = v.w;
        float4 w = *(const float4*)(Y + (size_t)(bn + row) * DD + k0 + k4 * 4);
        Bs[k4 * 4 + 0][row] = w.x; Bs[k4 * 4 + 1][row] = w.y;
        Bs[k4 * 4 + 2][row] = w.z; Bs[k4 * 4 + 3][row] = w.w;
      }
      __syncthreads();
      #pragma unroll
      for (int kk = 0; kk < GBK; kk++) {
        float4 a0 = *(const float4*)&As[kk][tr * 4];
        float4 a1 = *(const float4*)&As[kk][64 + tr * 4];
        float4 b0 = *(const float4*)&Bs[kk][tc * 4];
        float4 b1 = *(const float4*)&Bs[kk][64 + tc * 4];
        float av[2][4] = {{a0.x, a0.y, a0.z, a0.w}, {a1.x, a1.y, a1.z, a1.w}};
        float bv[2][4] = {{b0.x, b0.y, b0.z, b0.w}, {b1.x, b1.y, b1.z, b1.w}};
        #pragma unroll
        for (int i = 0; i < 2; i++)
          #pragma unroll
          for (int j = 0; j < 2; j++)
            #pragma unroll
            for (int x = 0; x < 4; x++)
              #pragma unroll
              for (int y = 0; y < 4; y++)
                acc[i][j][x][y] += av[i][x] * bv[j][y];
      }
      __syncthreads();
    }
    #pragma unroll
    for (int i = 0; i < 2; i++) {
      #pragma unroll
      for (int x = 0; x < 4; x++) {
        int r = bm + i * 64 + tr * 4 + x;
        if (r < 17 * CNUM) {
          #pragma unroll
          for (int j = 0; j < 2; j++) {
            float4 v = make_float4(acc[i][j][x][0], acc[i][j][x][1],
                                   acc[i][j][x][2], acc[i][j][x][3]);
            *(float4*)(out + (size_t)r * QNQ + bn + j * 64 + tc * 4) = v;
          }
        }
      }
    }
  } else {
    int wave = tid / 64, lane = tid % 64;
    int row = (b - 288) * 4 + wave;
    if (row >= 3136) return;
    bool isq = row < QNQ;
    const float* src = isq ? Xq + (size_t)row * DD
                     : (row < QNQ + NSUP) ? Xs + (size_t)(row - QNQ) * DD
                     : mu + (size_t)(row - QNQ - NSUP) * DD;
    const float* yr = Y + (size_t)row * DD;
    float s = 0.0f, s1 = 0.0f, s2 = 0.0f;
    for (int j4 = lane; j4 < 128; j4 += 64) {
      float4 v = *(const float4*)(src + j4 * 4);
      float4 uu = *(const float4*)(u + j4 * 4);
      s += v.x * uu.x + v.y * uu.y + v.z * uu.z + v.w * uu.w;
      if (isq) {
        s1 += v.x * v.x + v.y * v.y + v.z * v.z + v.w * v.w;
        float4 yv = *(const float4*)(yr + j4 * 4);
        s2 += yv.x * yv.x + yv.y * yv.y + yv.z * yv.z + yv.w * yv.w;
      }
    }
    for (int off = 32; off > 0; off >>= 1) {
      s += __shfl_down(s, off);
      s1 += __shfl_down(s1, off);
      s2 += __shfl_down(s2, off);
    }
    if (lane == 0) {
      z[row] = s;
      if (isq) {
        qn[row] = s1;
        qB[row] = s2 - cst[10] * s * s;
      }
    }
  }
}

// ============ F6: per-class Gram + inline 17x17 GJ inverse + bias ============
#define YSTRIDE 516
__global__ __launch_bounds__(256) void k_gramminv(const float* Y, const float* z,
    const int* rowmap, const float* cst, float* Vmu, float* muBmu,
    float* Minv, float* bias) {
  __shared__ float Ys[17 * YSTRIDE];
  __shared__ float zs[17];
  __shared__ float aug[17][35];
  __shared__ float colk[17];
  __shared__ int pivrow;
  __shared__ float detacc;
  int c = blockIdx.x, tid = threadIdx.x;
  for (int t = tid; t < 17 * 128; t += 256) {
    int r = t >> 7, col = t & 127;
    *(float4*)&Ys[r * YSTRIDE + col * 4] =
        *(const float4*)(Y + (size_t)rowmap[c * 17 + r] * DD + col * 4);
  }
  if (tid < 17) zs[tid] = z[rowmap[c * 17 + tid]];
  __syncthreads();
  float csm = cst[10];
  for (int e = tid; e < 289; e += 256) {
    int a = e / 17, bb = e % 17;
    const float* ra = &Ys[a * YSTRIDE];
    const float* rb = &Ys[bb * YSTRIDE];
    float s = 0.0f;
    for (int k = 0; k < 128; k++) {
      float4 va = *(const float4*)&ra[k * 4];
      float4 vb = *(const float4*)&rb[k * 4];
      s += va.x * vb.x + va.y * vb.y + va.z * vb.z + va.w * vb.w;
    }
    float g = s - csm * zs[a] * zs[bb];
    // augmented matrix: M = G + J^{-1} on diag
    if (a == bb) g += (a < 16) ? 1.0f : cst[9];
    aug[a][bb] = g;
    aug[a][17 + bb] = (a == bb) ? 1.0f : 0.0f;
  }
  __syncthreads();
  if (tid < 17) {
    // Vmu/muBmu from raw Gram: undo the diagonal add on the stored entries
    float gv = aug[tid][16];
    if (tid == 16) gv -= cst[9];
    Vmu[c * 17 + tid] = gv;
    if (tid == 16) muBmu[c] = gv;
  }
  if (tid == 0) detacc = 0.0f;
  __syncthreads();
  for (int k = 0; k < 17; k++) {
    if (tid == 0) {
      int p = k; float best = fabsf(aug[k][k]);
      for (int r = k + 1; r < 17; r++) {
        float v = fabsf(aug[r][k]);
        if (v > best) { best = v; p = r; }
      }
      pivrow = p;
    }
    __syncthreads();
    int p = pivrow;
    if (p != k) {
      for (int cc = tid; cc < 34; cc += 256) {
        float tmp = aug[k][cc]; aug[k][cc] = aug[p][cc]; aug[p][cc] = tmp;
      }
    }
    __syncthreads();
    if (tid == 0) detacc += logf(fabsf(aug[k][k]));
    if (tid < 17) colk[tid] = aug[tid][k];
    __syncthreads();
    float invp = 1.0f / aug[k][k];
    for (int cc = tid; cc < 34; cc += 256) aug[k][cc] *= invp;
    __syncthreads();
    for (int t = tid; t < 17 * 34; t += 256) {
      int r = t / 34, cc = t % 34;
      if (r != k) aug[r][cc] -= colk[r] * aug[k][cc];
    }
    __syncthreads();
  }
  for (int t = tid; t < 289; t += 256) Minv[(size_t)c * 289 + t] = aug[t / 17][17 + t % 17];
  if (tid == 0) {
    float slog = logf(fabsf(cst[5])) + detacc;
    float logdetSigma = cst[8] + cst[11] + slog;
    bias[c] = cst[4] - 0.5f * logdetSigma;
  }
}

// final epilogue: Woodbury-corrected Mahalanobis -> logits[q,c]
__global__ __launch_bounds__(256) void k_logits(const float* __restrict__ Rg,
    const float* __restrict__ Rg2, const float* z, const int* rowmap,
    const float* Vmu, const float* muBmu, const float* mun, const float* qB,
    const float* qn, const float* xmup, const float* Minv, const float* bias,
    const float* cst, float* out) {
  __shared__ float Ms[289], Vs[17], Zs[17];
  int c = blockIdx.y;
  int q = blockIdx.x * 256 + threadIdx.x;
  for (int t = threadIdx.x; t < 289; t += 256) Ms[t] = Minv[(size_t)c * 289 + t];
  if (threadIdx.x < 17) {
    Vs[threadIdx.x] = Vmu[c * 17 + threadIdx.x];
    Zs[threadIdx.x] = z[rowmap[c * 17 + threadIdx.x]];
  }
  __syncthreads();
  float csm = cst[10], scale = cst[1], common = cst[2], coef = cst[3];
  float zq = z[q];
  float r[17];
  float xBmu = 0.0f;
  for (int a = 0; a < 17; a++) {
    size_t off = (size_t)(c * 17 + a) * QNQ + q;
    float raw = Rg[off] + Rg2[off] - csm * Zs[a] * zq;
    if (a == 16) xBmu = raw;
    r[a] = raw - Vs[a];
  }
  float quadB = qB[q] - 2.0f * xBmu + muBmu[c];
  float corr = 0.0f;
  for (int a = 0; a < 17; a++) {
    float e = 0.0f;
    for (int b = 0; b < 17; b++) e += Ms[a * 17 + b] * r[b];
    corr += r[a] * e;
  }
  float distB = (quadB - corr) / scale;
  float xm = 0.0f;
  #pragma unroll
  for (int p = 0; p < XKS; p++)
    xm += xmup[((size_t)p * QNQ + q) * CNUM + c];
  float dn = qn[q] - 2.0f * xm + mun[c];
  float dist = (1.0f - REGP) * distB + REGP * dn;
  out[(size_t)q * CNUM + c] = bias[c] - coef * log1pf(dist / common);
}

// ---------------- host ----------------
extern "C" void kernel_launch(void* const* d_in, const int* in_sizes, int n_in,
                              void* d_out, int out_size, void* d_ws, size_t ws_size,
                              hipStream_t stream) {
  const float* Xs    = (const float*)d_in[0];
  const int*   labels= (const int*)d_in[1];
  const float* Xq    = (const float*)d_in[2];
  const float* m     = (const float*)d_in[3];
  const float* kappa = (const float*)d_in[4];
  const float* nu    = (const float*)d_in[5];
  const float* tdiag = (const float*)d_in[6];
  const float* tlow  = (const float*)d_in[7];
  float* ws = (float*)d_ws;
  float* L    = ws + OFF_L;
  float* W    = ws + OFF_W;
  float* mu   = ws + OFF_MU;
  float* Y    = ws + OFF_Y;
  float* z    = ws + OFF_Z;
  float* wm   = ws + OFF_WM;
  float* u    = ws + OFF_U;
  float* cst  = ws + OFF_CONST;
  int*   idx  = (int*)(ws + OFF_IDX);
  int*   rmap = (int*)(ws + OFF_RMAP);
  float* Vmu  = ws + OFF_VMU;
  float* muBmu= ws + OFF_MUBMU;
  float* mun  = ws + OFF_MUN;
  float* Minv = ws + OFF_MINV;
  float* bias = ws + OFF_BIAS;
  float* qB   = ws + OFF_QB;
  float* qn   = ws + OFF_QNRM;
  float* xmup = ws + OFF_XMU;
  float* Rg   = ws + OFF_RG;
  float* Rg2  = ws + OFF_RG2;
  float* Ttmp = ws + OFF_RG;       // trinv scratch, reused (Rg written later)
  float* out  = (float*)d_out;

  // F1: L/W init + consts + classidx
  f_init<<<1089, 256, 0, stream>>>(tdiag, tlow, kappa, nu, labels, L, W, cst, idx, rmap);
  // F2: mu/mun + trinv diagonal blocks
  f_mu_diag<<<72, 256, 0, stream>>>(Xs, m, idx, cst, mu, mun, L, W);
  // trinv recursive doubling levels
  for (int s = 128; s <= 512; s <<= 1) {
    int h = s >> 1, tiles = h >> 6, supers = 512 / s;
    int nblk = supers * tiles * tiles;
    k_triT<<<nblk, 256, 0, stream>>>(L, W, Ttmp, s);
    k_triX<<<nblk, 256, 0, stream>>>(W, Ttmp, s);
  }
  // F3: Y GEMM + wm + xmu
  f_y_wm_xmu<<<584, 256, 0, stream>>>(Xq, Xs, mu, W, m, Y, wm, xmup);
  // u = W^T wm + SM consts
  k_uB<<<513, 256, 0, stream>>>(W, L, wm, u, cst);
  // F5: Rg split-K GEMM + z/qn/qB
  f_z_rg<<<288 + 784, 256, 0, stream>>>(Y, rmap, Xq, Xs, mu, u, cst,
                                        Rg, Rg2, z, qn, qB);
  // F6: Gram + 17x17 inverse + bias
  k_gramminv<<<64, 256, 0, stream>>>(Y, z, rmap, cst, Vmu, muBmu, Minv, bias);
  k_logits<<<dim3(QNQ / 256, CNUM), 256, 0, stream>>>(Rg, Rg2, z, rmap, Vmu, muBmu,
                                                      mun, qB, qn, xmup, Minv, bias,
                                                      cst, out);
  (void)in_sizes; (void)n_in; (void)out_size; (void)ws_size;
}

// Round 7
// 274.734 us; speedup vs baseline: 1.1682x; 1.1682x over previous
//
#include <hip/hip_runtime.h>
#include <math.h>

// Problem dims (fixed by setup_inputs)
#define DD    512
#define CNUM  64
#define SHOTS 16
#define NSUP  1024
#define QNQ   2048
#define REGP  0.1f
#define XKS   4      // xmu split-K parts

// ---------------- workspace layout (in floats) ----------------
static constexpr size_t OFF_L     = 0;                       // 512*512
static constexpr size_t OFF_W     = OFF_L     + 512*512;     // 512*512
static constexpr size_t OFF_MU    = OFF_W     + 512*512;     // 64*512
static constexpr size_t OFF_Y     = OFF_MU    + 64*512;      // 3136*512
static constexpr size_t OFF_Z     = OFF_Y     + 3136*512;    // 3136
static constexpr size_t OFF_WM    = OFF_Z     + 3136;        // 512
static constexpr size_t OFF_U     = OFF_WM    + 512;         // 512
static constexpr size_t OFF_CONST = OFF_U     + 512;         // 32
static constexpr size_t OFF_IDX   = OFF_CONST + 32;          // 1024 ints
static constexpr size_t OFF_RMAP  = OFF_IDX   + 1024;        // 1088 ints
static constexpr size_t OFF_VMU   = OFF_RMAP  + 1088;        // 1088
static constexpr size_t OFF_MUBMU = OFF_VMU   + 1088;        // 64
static constexpr size_t OFF_MUN   = OFF_MUBMU + 64;          // 64
static constexpr size_t OFF_MINV  = OFF_MUN   + 64;          // 64*289
static constexpr size_t OFF_BIAS  = OFF_MINV  + 64*289;      // 64
static constexpr size_t OFF_QB    = OFF_BIAS  + 64;          // 2048
static constexpr size_t OFF_QNRM  = OFF_QB    + 2048;        // 2048
static constexpr size_t OFF_XMU   = OFF_QNRM  + 2048;        // XKS*2048*64
static constexpr size_t OFF_RG    = OFF_XMU   + (size_t)XKS*2048*64; // 1088*2048
static constexpr size_t OFF_RG2   = OFF_RG    + 1088*2048;   // 1088*2048

// consts: 0 kap, 1 scale, 2 common, 3 coef, 4 bias0, 5 jlast,
// 6 cmu_m, 7 cmu_x, 8 D*log(scale), 9 Jinv_last, 10 c_sm, 11 logdetB

// ============ F1: init L/W + consts + classidx (one launch) ============
__global__ __launch_bounds__(256) void f_init(const float* tdiag, const float* tlow,
    const float* kappa, const float* nu, const int* labels,
    float* L, float* W, float* cst, int* idx, int* rowmap) {
  int b = blockIdx.x, tid = threadIdx.x;
  if (b < 1024) {
    int t = b * 256 + tid;
    int i = t / DD, j = t % DD;
    L[t] = (i == j) ? fabsf(tdiag[i]) : (i > j ? tlow[t] : 0.0f);
    W[t] = 0.0f;
  } else if (b == 1024) {
    if (tid == 0) {
      float kap = fabsf(kappa[0]) + 1e-6f;
      float nu_ = fmaxf(nu[0], (float)(DD - 1) + 1e-6f);
      float common = nu_ + (float)SHOTS + 1.0f - (float)DD;
      float scale = (kap + SHOTS + 1.0f) / ((nu_ + SHOTS - DD + 1.0f) * (kap + SHOTS));
      cst[0] = kap;
      cst[1] = scale;
      cst[2] = common;
      cst[3] = 0.5f * (common + DD);
      cst[4] = lgammaf(0.5f * (common + DD)) - lgammaf(0.5f * common)
               - 0.5f * (float)DD * logf(common);
      cst[5] = -(kap + SHOTS);
      cst[6] = kap / (kap + SHOTS);
      cst[7] = 1.0f / (kap + SHOTS);
      cst[8] = (float)DD * logf(scale);
      cst[9] = -1.0f / (kap + SHOTS);
    }
  } else {
    int c = b - 1025;
    if (tid < 64) {
      int lane = tid, cnt = 0;
      for (int i0 = 0; i0 < NSUP; i0 += 64) {
        int lab = labels[i0 + lane];
        unsigned long long m = __ballot(lab == c);
        if (lab == c) {
          int pos = cnt + __popcll(m & ((1ull << lane) - 1ull));
          if (pos < SHOTS) idx[c * SHOTS + pos] = i0 + lane;
        }
        cnt += __popcll(m);
      }
    }
    __syncthreads();
    if (tid < 17)
      rowmap[c * 17 + tid] = (tid < SHOTS) ? (QNQ + idx[c * SHOTS + tid])
                                           : (QNQ + NSUP + c);
  }
}

// ============ F2: mu (+||mu||^2) + trinv diag blocks (one launch) ============
__global__ __launch_bounds__(256) void f_mu_diag(const float* Xs, const float* m,
    const int* idx, const float* cst, float* mu, float* mun,
    const float* L, float* W) {
  __shared__ float red[256];
  __shared__ float Ld[64][65];
  __shared__ float Wd[64][65];
  int b = blockIdx.x, tid = threadIdx.x;
  if (b < 64) {
    int c = b;
    float cm = cst[6], cx = cst[7];
    float acc = 0.0f;
    for (int d = tid; d < DD; d += 256) {
      float s = 0.0f;
      for (int sh = 0; sh < SHOTS; sh++)
        s += Xs[(size_t)idx[c * SHOTS + sh] * DD + d];
      float v = cm * m[d] + cx * s;
      mu[(size_t)c * DD + d] = v;
      acc += v * v;
    }
    red[tid] = acc;
    __syncthreads();
    for (int off = 128; off > 0; off >>= 1) {
      if (tid < off) red[tid] += red[tid + off];
      __syncthreads();
    }
    if (tid == 0) mun[c] = red[0];
  } else {
    int jb = b - 64;
    const float* Lblk = L + (size_t)(jb * 64) * DD + jb * 64;
    if (tid < 64)
      for (int r = 0; r < 64; r++) Ld[r][tid] = Lblk[(size_t)r * DD + tid];
    __syncthreads();
    if (tid < 64) {
      for (int i = 0; i < 64; i++) {
        float w = (i == tid) ? 1.0f : 0.0f;
        for (int k = 0; k < i; k++) w -= Ld[i][k] * Wd[k][tid];
        Wd[i][tid] = w / Ld[i][i];
      }
      float* Wblk = W + (size_t)(jb * 64) * DD + jb * 64;
      for (int r = 0; r < 64; r++) Wblk[(size_t)r * DD + tid] = Wd[r][tid];
    }
  }
}

// ---------------- trinv: recursive doubling GEMM tile (64x64 out) ----------------
__device__ __forceinline__ void nn64_body(const float* __restrict__ A, int lda,
                                          const float* __restrict__ B, int ldb,
                                          float* __restrict__ Cd, int ldc,
                                          int k0, int k1, float sgn) {
  __shared__ float As[64][68];
  __shared__ float Bs[64][68];
  int tid = threadIdx.x, tr = tid >> 4, tc = tid & 15;
  float acc[4][4] = {};
  for (int kc = k0; kc < k1; kc += 64) {
    #pragma unroll
    for (int p = 0; p < 4; p++) {
      int f4 = tid + 256 * p;
      int row = f4 >> 4, c4 = f4 & 15;
      *(float4*)&As[row][c4 * 4] = *(const float4*)(A + (size_t)row * lda + kc + c4 * 4);
      *(float4*)&Bs[row][c4 * 4] = *(const float4*)(B + (size_t)(kc + row) * ldb + c4 * 4);
    }
    __syncthreads();
    #pragma unroll
    for (int kk = 0; kk < 64; kk++) {
      float a[4];
      #pragma unroll
      for (int x = 0; x < 4; x++) a[x] = As[tr * 4 + x][kk];
      float4 bv = *(const float4*)&Bs[kk][tc * 4];
      float b[4] = {bv.x, bv.y, bv.z, bv.w};
      #pragma unroll
      for (int x = 0; x < 4; x++)
        #pragma unroll
        for (int y = 0; y < 4; y++) acc[x][y] += a[x] * b[y];
    }
    __syncthreads();
  }
  #pragma unroll
  for (int x = 0; x < 4; x++) {
    float4 v = make_float4(sgn * acc[x][0], sgn * acc[x][1],
                           sgn * acc[x][2], sgn * acc[x][3]);
    *(float4*)(Cd + (size_t)(tr * 4 + x) * ldc + tc * 4) = v;
  }
}

__global__ __launch_bounds__(256) void k_triT(const float* __restrict__ L,
                                              const float* __restrict__ W,
                                              float* __restrict__ T, int s) {
  int h = s >> 1, tiles = h >> 6, per = tiles * tiles;
  int g = blockIdx.x / per, rem = blockIdx.x % per;
  int ti = rem / tiles, tj = rem % tiles;
  int base = g * s;
  const float* A = L + (size_t)(base + h + ti * 64) * DD + base;
  const float* B = W + (size_t)base * DD + base + tj * 64;
  float* Cd = T + (size_t)g * h * h + (size_t)(ti * 64) * h + tj * 64;
  nn64_body(A, DD, B, DD, Cd, h, tj * 64, h, 1.0f);
}

__global__ __launch_bounds__(256) void k_triX(float* __restrict__ W,
                                              const float* __restrict__ T, int s) {
  int h = s >> 1, tiles = h >> 6, per = tiles * tiles;
  int g = blockIdx.x / per, rem = blockIdx.x % per;
  int ti = rem / tiles, tj = rem % tiles;
  int base = g * s;
  const float* A = W + (size_t)(base + h + ti * 64) * DD + base + h;
  const float* B = T + (size_t)g * h * h + tj * 64;
  float* Cd = W + (size_t)(base + h + ti * 64) * DD + base + tj * 64;
  nn64_body(A, DD, B, h, Cd, DD, 0, (ti + 1) * 64, -1.0f);
}

#define GBK 16
// ============ F3: Y-GEMM (64x64, tri-skip) + wm + xmu (one launch) ============
__global__ __launch_bounds__(256) void f_y_wm_xmu(const float* __restrict__ Xq,
    const float* __restrict__ Xs, const float* __restrict__ Mu,
    const float* __restrict__ W, const float* __restrict__ m,
    float* __restrict__ Y, float* __restrict__ wm, float* __restrict__ xmup) {
  __shared__ float As[GBK][68];
  __shared__ float Bs[GBK][68];
  int b = blockIdx.x, tid = threadIdx.x;
  if (b < 392) {            // Y = [Xq; Xs; mu] @ W^T; 49 m-tiles x 8 n-tiles, 64x64
    int mt = b >> 3, nt = b & 7;
    int bm = mt * 64, bn = nt * 64;
    const float* A; int aOff;
    if (bm < QNQ)             { A = Xq; aOff = bm; }
    else if (bm < QNQ + NSUP) { A = Xs; aOff = bm - QNQ; }
    else                      { A = Mu; aOff = bm - QNQ - NSUP; }
    int tr = tid >> 4, tc = tid & 15;
    float acc[4][4] = {};
    int kend = bn + 64;     // W lower-triangular
    for (int k0 = 0; k0 < kend; k0 += GBK) {
      int row = tid >> 2, k4 = tid & 3;
      float4 v = *(const float4*)(A + (size_t)(aOff + row) * DD + k0 + k4 * 4);
      As[k4 * 4 + 0][row] = v.x; As[k4 * 4 + 1][row] = v.y;
      As[k4 * 4 + 2][row] = v.z; As[k4 * 4 + 3][row] = v.w;
      float4 w = *(const float4*)(W + (size_t)(bn + row) * DD + k0 + k4 * 4);
      Bs[k4 * 4 + 0][row] = w.x; Bs[k4 * 4 + 1][row] = w.y;
      Bs[k4 * 4 + 2][row] = w.z; Bs[k4 * 4 + 3][row] = w.w;
      __syncthreads();
      #pragma unroll
      for (int kk = 0; kk < GBK; kk++) {
        float4 a0 = *(const float4*)&As[kk][tr * 4];
        float4 b0 = *(const float4*)&Bs[kk][tc * 4];
        float a[4] = {a0.x, a0.y, a0.z, a0.w};
        float bb[4] = {b0.x, b0.y, b0.z, b0.w};
        #pragma unroll
        for (int x = 0; x < 4; x++)
          #pragma unroll
          for (int y = 0; y < 4; y++) acc[x][y] += a[x] * bb[y];
      }
      __syncthreads();
    }
    #pragma unroll
    for (int x = 0; x < 4; x++) {
      float4 v = make_float4(acc[x][0], acc[x][1], acc[x][2], acc[x][3]);
      *(float4*)(Y + (size_t)(bm + tr * 4 + x) * DD + bn + tc * 4) = v;
    }
  } else if (b < 520) {     // wm[row] = W[row,:] . m  (4 rows/block)
    int wave = tid / 64, lane = tid % 64;
    int row = (b - 392) * 4 + wave;
    float s = 0.0f;
    for (int j = lane; j < DD; j += 64) s += W[(size_t)row * DD + j] * m[j];
    for (int off = 32; off > 0; off >>= 1) s += __shfl_down(s, off);
    if (lane == 0) wm[row] = s;
  } else {                  // xmu partials: 32 q-rows, split-K=4
    int xb = b - 520;
    int bm = (xb & 63) * 32, kq = xb >> 6;
    int tr = tid >> 4, tc = tid & 15;
    float acc[2][4] = {};
    int k0s = kq * (DD / XKS), k0e = k0s + DD / XKS;
    for (int k0 = k0s; k0 < k0e; k0 += GBK) {
      if (tid < 128) {
        int row = tid >> 2, k4 = tid & 3;
        float4 v = *(const float4*)(Xq + (size_t)(bm + row) * DD + k0 + k4 * 4);
        As[k4 * 4 + 0][row] = v.x; As[k4 * 4 + 1][row] = v.y;
        As[k4 * 4 + 2][row] = v.z; As[k4 * 4 + 3][row] = v.w;
      }
      {
        int row = tid >> 2, k4 = tid & 3;
        float4 v = *(const float4*)(Mu + (size_t)row * DD + k0 + k4 * 4);
        Bs[k4 * 4 + 0][row] = v.x; Bs[k4 * 4 + 1][row] = v.y;
        Bs[k4 * 4 + 2][row] = v.z; Bs[k4 * 4 + 3][row] = v.w;
      }
      __syncthreads();
      #pragma unroll
      for (int kk = 0; kk < GBK; kk++) {
        float a[2] = {As[kk][tr * 2], As[kk][tr * 2 + 1]};
        float4 b0 = *(const float4*)&Bs[kk][tc * 4];
        float bb[4] = {b0.x, b0.y, b0.z, b0.w};
        #pragma unroll
        for (int x = 0; x < 2; x++)
          #pragma unroll
          for (int y = 0; y < 4; y++) acc[x][y] += a[x] * bb[y];
      }
      __syncthreads();
    }
    #pragma unroll
    for (int x = 0; x < 2; x++) {
      int q = bm + tr * 2 + x;
      float4 v = make_float4(acc[x][0], acc[x][1], acc[x][2], acc[x][3]);
      *(float4*)(xmup + ((size_t)kq * QNQ + q) * CNUM + tc * 4) = v;
    }
  }
}

// fused: blocks 0..511 compute u[j]; block 512 computes SM consts
__global__ __launch_bounds__(256) void k_uB(const float* W, const float* L,
                                            const float* wm, float* u, float* cst) {
  __shared__ float red[256];
  __shared__ float red2[256];
  int b = blockIdx.x, tid = threadIdx.x;
  if (b < DD) {
    float s = 0.0f;
    for (int i = tid; i < DD; i += 256) s += W[(size_t)i * DD + b] * wm[i];
    red[tid] = s;
    __syncthreads();
    for (int off = 128; off > 0; off >>= 1) {
      if (tid < off) red[tid] += red[tid + off];
      __syncthreads();
    }
    if (tid == 0) u[b] = red[0];
  } else {
    float a = 0.0f, l = 0.0f;
    for (int t = tid; t < DD; t += 256) {
      float w = wm[t]; a += w * w;
      l += logf(fabsf(L[(size_t)t * DD + t]));
    }
    red[tid] = a; red2[tid] = l;
    __syncthreads();
    for (int off = 128; off > 0; off >>= 1) {
      if (tid < off) { red[tid] += red[tid + off]; red2[tid] += red2[tid + off]; }
      __syncthreads();
    }
    if (tid == 0) {
      float kap = cst[0], ss = red[0];
      cst[10] = kap / (1.0f + kap * ss);
      cst[11] = 2.0f * red2[0] + logf(1.0f + kap * ss);
    }
  }
}

// ============ F5: Rg GEMM (64x64, 4x4/thread, split-K=2 -> 1088 blocks) + z ============
__global__ __launch_bounds__(256) void f_z_rg(const float* __restrict__ Y,
    const int* __restrict__ rowmap, const float* __restrict__ Xq,
    const float* __restrict__ Xs, const float* __restrict__ mu,
    const float* __restrict__ u, const float* __restrict__ cst,
    float* __restrict__ Rg, float* __restrict__ Rg2,
    float* __restrict__ z, float* __restrict__ qn, float* __restrict__ qB) {
  __shared__ float As[GBK][68];
  __shared__ float Bs[GBK][68];
  int b = blockIdx.x, tid = threadIdx.x;
  if (b < 1088) {           // 17 m-tiles x 32 n-tiles x 2 K-halves, 64x64 out
    int half = b / 544, rem = b % 544;
    int bm = (rem >> 5) * 64, bn = (rem & 31) * 64;
    float* out = half ? Rg2 : Rg;
    int tr = tid >> 4, tc = tid & 15;
    int srow = rowmap[bm + (tid >> 2)];       // gathered A row for staging
    float acc[4][4] = {};
    int k0s = half * 256;
    for (int k0 = k0s; k0 < k0s + 256; k0 += GBK) {
      int row = tid >> 2, k4 = tid & 3;
      float4 v = *(const float4*)(Y + (size_t)srow * DD + k0 + k4 * 4);
      As[k4 * 4 + 0][row] = v.x; As[k4 * 4 + 1][row] = v.y;
      As[k4 * 4 + 2][row] = v.z; As[k4 * 4 + 3][row] = v.w;
      float4 w = *(const float4*)(Y + (size_t)(bn + row) * DD + k0 + k4 * 4);
      Bs[k4 * 4 + 0][row] = w.x; Bs[k4 * 4 + 1][row] = w.y;
      Bs[k4 * 4 + 2][row] = w.z; Bs[k4 * 4 + 3][row] = w.w;
      __syncthreads();
      #pragma unroll
      for (int kk = 0; kk < GBK; kk++) {
        float4 a0 = *(const float4*)&As[kk][tr * 4];
        float4 b0 = *(const float4*)&Bs[kk][tc * 4];
        float a[4] = {a0.x, a0.y, a0.z, a0.w};
        float bb[4] = {b0.x, b0.y, b0.z, b0.w};
        #pragma unroll
        for (int x = 0; x < 4; x++)
          #pragma unroll
          for (int y = 0; y < 4; y++) acc[x][y] += a[x] * bb[y];
      }
      __syncthreads();
    }
    #pragma unroll
    for (int x = 0; x < 4; x++) {
      float4 v = make_float4(acc[x][0], acc[x][1], acc[x][2], acc[x][3]);
      *(float4*)(out + (size_t)(bm + tr * 4 + x) * QNQ + bn + tc * 4) = v;
    }
  } else {
    int wave = tid / 64, lane = tid % 64;
    int row = (b - 1088) * 4 + wave;
    if (row >= 3136) return;
    bool isq = row < QNQ;
    const float* src = isq ? Xq + (size_t)row * DD
                     : (row < QNQ + NSUP) ? Xs + (size_t)(row - QNQ) * DD
                     : mu + (size_t)(row - QNQ - NSUP) * DD;
    const float* yr = Y + (size_t)row * DD;
    float s = 0.0f, s1 = 0.0f, s2 = 0.0f;
    for (int j4 = lane; j4 < 128; j4 += 64) {
      float4 v = *(const float4*)(src + j4 * 4);
      float4 uu = *(const float4*)(u + j4 * 4);
      s += v.x * uu.x + v.y * uu.y + v.z * uu.z + v.w * uu.w;
      if (isq) {
        s1 += v.x * v.x + v.y * v.y + v.z * v.z + v.w * v.w;
        float4 yv = *(const float4*)(yr + j4 * 4);
        s2 += yv.x * yv.x + yv.y * yv.y + yv.z * yv.z + yv.w * yv.w;
      }
    }
    for (int off = 32; off > 0; off >>= 1) {
      s += __shfl_down(s, off);
      s1 += __shfl_down(s1, off);
      s2 += __shfl_down(s2, off);
    }
    if (lane == 0) {
      z[row] = s;
      if (isq) {
        qn[row] = s1;
        qB[row] = s2 - cst[10] * s * s;
      }
    }
  }
}

// ============ F6: per-class Gram + inline 17x17 GJ inverse + bias ============
#define YSTRIDE 516
__global__ __launch_bounds__(256) void k_gramminv(const float* Y, const float* z,
    const int* rowmap, const float* cst, float* Vmu, float* muBmu,
    float* Minv, float* bias) {
  __shared__ float Ys[17 * YSTRIDE];
  __shared__ float zs[17];
  __shared__ float aug[17][35];
  __shared__ float colk[17];
  __shared__ int pivrow;
  __shared__ float detacc;
  int c = blockIdx.x, tid = threadIdx.x;
  for (int t = tid; t < 17 * 128; t += 256) {
    int r = t >> 7, col = t & 127;
    *(float4*)&Ys[r * YSTRIDE + col * 4] =
        *(const float4*)(Y + (size_t)rowmap[c * 17 + r] * DD + col * 4);
  }
  if (tid < 17) zs[tid] = z[rowmap[c * 17 + tid]];
  __syncthreads();
  float csm = cst[10];
  for (int e = tid; e < 289; e += 256) {
    int a = e / 17, bb = e % 17;
    const float* ra = &Ys[a * YSTRIDE];
    const float* rb = &Ys[bb * YSTRIDE];
    float s = 0.0f;
    for (int k = 0; k < 128; k++) {
      float4 va = *(const float4*)&ra[k * 4];
      float4 vb = *(const float4*)&rb[k * 4];
      s += va.x * vb.x + va.y * vb.y + va.z * vb.z + va.w * vb.w;
    }
    float g = s - csm * zs[a] * zs[bb];
    if (a == bb) g += (a < 16) ? 1.0f : cst[9];
    aug[a][bb] = g;
    aug[a][17 + bb] = (a == bb) ? 1.0f : 0.0f;
  }
  __syncthreads();
  if (tid < 17) {
    float gv = aug[tid][16];
    if (tid == 16) gv -= cst[9];
    Vmu[c * 17 + tid] = gv;
    if (tid == 16) muBmu[c] = gv;
  }
  if (tid == 0) detacc = 0.0f;
  __syncthreads();
  for (int k = 0; k < 17; k++) {
    if (tid == 0) {
      int p = k; float best = fabsf(aug[k][k]);
      for (int r = k + 1; r < 17; r++) {
        float v = fabsf(aug[r][k]);
        if (v > best) { best = v; p = r; }
      }
      pivrow = p;
    }
    __syncthreads();
    int p = pivrow;
    if (p != k) {
      for (int cc = tid; cc < 34; cc += 256) {
        float tmp = aug[k][cc]; aug[k][cc] = aug[p][cc]; aug[p][cc] = tmp;
      }
    }
    __syncthreads();
    if (tid == 0) detacc += logf(fabsf(aug[k][k]));
    if (tid < 17) colk[tid] = aug[tid][k];
    __syncthreads();
    float invp = 1.0f / aug[k][k];
    for (int cc = tid; cc < 34; cc += 256) aug[k][cc] *= invp;
    __syncthreads();
    for (int t = tid; t < 17 * 34; t += 256) {
      int r = t / 34, cc = t % 34;
      if (r != k) aug[r][cc] -= colk[r] * aug[k][cc];
    }
    __syncthreads();
  }
  for (int t = tid; t < 289; t += 256) Minv[(size_t)c * 289 + t] = aug[t / 17][17 + t % 17];
  if (tid == 0) {
    float slog = logf(fabsf(cst[5])) + detacc;
    float logdetSigma = cst[8] + cst[11] + slog;
    bias[c] = cst[4] - 0.5f * logdetSigma;
  }
}

// final epilogue: Woodbury-corrected Mahalanobis -> logits[q,c]
__global__ __launch_bounds__(256) void k_logits(const float* __restrict__ Rg,
    const float* __restrict__ Rg2, const float* z, const int* rowmap,
    const float* Vmu, const float* muBmu, const float* mun, const float* qB,
    const float* qn, const float* xmup, const float* Minv, const float* bias,
    const float* cst, float* out) {
  __shared__ float Ms[289], Vs[17], Zs[17];
  int c = blockIdx.y;
  int q = blockIdx.x * 256 + threadIdx.x;
  for (int t = threadIdx.x; t < 289; t += 256) Ms[t] = Minv[(size_t)c * 289 + t];
  if (threadIdx.x < 17) {
    Vs[threadIdx.x] = Vmu[c * 17 + threadIdx.x];
    Zs[threadIdx.x] = z[rowmap[c * 17 + threadIdx.x]];
  }
  __syncthreads();
  float csm = cst[10], scale = cst[1], common = cst[2], coef = cst[3];
  float zq = z[q];
  float r[17];
  float xBmu = 0.0f;
  for (int a = 0; a < 17; a++) {
    size_t off = (size_t)(c * 17 + a) * QNQ + q;
    float raw = Rg[off] + Rg2[off] - csm * Zs[a] * zq;
    if (a == 16) xBmu = raw;
    r[a] = raw - Vs[a];
  }
  float quadB = qB[q] - 2.0f * xBmu + muBmu[c];
  float corr = 0.0f;
  for (int a = 0; a < 17; a++) {
    float e = 0.0f;
    for (int b = 0; b < 17; b++) e += Ms[a * 17 + b] * r[b];
    corr += r[a] * e;
  }
  float distB = (quadB - corr) / scale;
  float xm = 0.0f;
  #pragma unroll
  for (int p = 0; p < XKS; p++)
    xm += xmup[((size_t)p * QNQ + q) * CNUM + c];
  float dn = qn[q] - 2.0f * xm + mun[c];
  float dist = (1.0f - REGP) * distB + REGP * dn;
  out[(size_t)q * CNUM + c] = bias[c] - coef * log1pf(dist / common);
}

// ---------------- host ----------------
extern "C" void kernel_launch(void* const* d_in, const int* in_sizes, int n_in,
                              void* d_out, int out_size, void* d_ws, size_t ws_size,
                              hipStream_t stream) {
  const float* Xs    = (const float*)d_in[0];
  const int*   labels= (const int*)d_in[1];
  const float* Xq    = (const float*)d_in[2];
  const float* m     = (const float*)d_in[3];
  const float* kappa = (const float*)d_in[4];
  const float* nu    = (const float*)d_in[5];
  const float* tdiag = (const float*)d_in[6];
  const float* tlow  = (const float*)d_in[7];
  float* ws = (float*)d_ws;
  float* L    = ws + OFF_L;
  float* W    = ws + OFF_W;
  float* mu   = ws + OFF_MU;
  float* Y    = ws + OFF_Y;
  float* z    = ws + OFF_Z;
  float* wm   = ws + OFF_WM;
  float* u    = ws + OFF_U;
  float* cst  = ws + OFF_CONST;
  int*   idx  = (int*)(ws + OFF_IDX);
  int*   rmap = (int*)(ws + OFF_RMAP);
  float* Vmu  = ws + OFF_VMU;
  float* muBmu= ws + OFF_MUBMU;
  float* mun  = ws + OFF_MUN;
  float* Minv = ws + OFF_MINV;
  float* bias = ws + OFF_BIAS;
  float* qB   = ws + OFF_QB;
  float* qn   = ws + OFF_QNRM;
  float* xmup = ws + OFF_XMU;
  float* Rg   = ws + OFF_RG;
  float* Rg2  = ws + OFF_RG2;
  float* Ttmp = ws + OFF_RG;       // trinv scratch, reused (Rg written later)
  float* out  = (float*)d_out;

  // F1: L/W init + consts + classidx
  f_init<<<1089, 256, 0, stream>>>(tdiag, tlow, kappa, nu, labels, L, W, cst, idx, rmap);
  // F2: mu/mun + trinv diagonal blocks
  f_mu_diag<<<72, 256, 0, stream>>>(Xs, m, idx, cst, mu, mun, L, W);
  // trinv recursive doubling levels
  for (int s = 128; s <= 512; s <<= 1) {
    int h = s >> 1, tiles = h >> 6, supers = 512 / s;
    int nblk = supers * tiles * tiles;
    k_triT<<<nblk, 256, 0, stream>>>(L, W, Ttmp, s);
    k_triX<<<nblk, 256, 0, stream>>>(W, Ttmp, s);
  }
  // F3: Y GEMM (64x64) + wm + xmu
  f_y_wm_xmu<<<776, 256, 0, stream>>>(Xq, Xs, mu, W, m, Y, wm, xmup);
  // u = W^T wm + SM consts
  k_uB<<<513, 256, 0, stream>>>(W, L, wm, u, cst);
  // F5: Rg split-K GEMM (64x64 tiles, 1088 blocks) + z/qn/qB
  f_z_rg<<<1088 + 784, 256, 0, stream>>>(Y, rmap, Xq, Xs, mu, u, cst,
                                         Rg, Rg2, z, qn, qB);
  // F6: Gram + 17x17 inverse + bias
  k_gramminv<<<64, 256, 0, stream>>>(Y, z, rmap, cst, Vmu, muBmu, Minv, bias);
  k_logits<<<dim3(QNQ / 256, CNUM), 256, 0, stream>>>(Rg, Rg2, z, rmap, Vmu, muBmu,
                                                      mun, qB, qn, xmup, Minv, bias,
                                                      cst, out);
  (void)in_sizes; (void)n_in; (void)out_size; (void)ws_size;
}